// Round 1
// baseline (1113.828 us; speedup 1.0000x reference)
//
#include <hip/hip_runtime.h>
#include <math.h>

// Problem constants
#define HW   16384        // 128*128
#define CC   256
#define cC   64
#define BB   16
#define CHW  (CC*HW)      // 4194304 = 2^22
#define cHW  (cC*HW)      // 1048576

// ws float offsets
#define WS_T    0
#define WS_W2E  16777216
#define WS_K1E  (WS_W2E + 5184)
#define WS_GN1A (WS_K1E + 16)       // 512 floats
#define WS_GNSA (WS_GN1A + 512)
#define WS_GN2A (WS_GNSA + 512)
#define WS_SC1  (WS_GN2A + 512)     // 1024
#define WS_SH1  (WS_SC1 + 1024)
#define WS_SCS  (WS_SH1 + 1024)
#define WS_SHS  (WS_SCS + 1024)
#define WS_SC2  (WS_SHS + 1024)     // 4096
#define WS_SH2  (WS_SC2 + 4096)

// ---------------------------------------------------------------------------
// K0: compute effective kernels k1_eff[9], W2_eff[64*81]; zero GN accumulators
// ---------------------------------------------------------------------------
__global__ void k_setup(const float* __restrict__ W1, const float* __restrict__ W2,
                        float* __restrict__ k1e, float* __restrict__ w2e,
                        float* __restrict__ accz) {
    __shared__ float tapsum[81];
    __shared__ float a2s[4];
    int tdx = threadIdx.x;
    for (int i = tdx; i < 1536; i += 128) accz[i] = 0.f;   // gn1a|gnsa|gn2a contiguous
    if (tdx < 81) {
        float s = 0.f;
        for (int ch = 0; ch < 64; ++ch) s += W2[ch * 81 + tdx];
        tapsum[tdx] = s;
    }
    __syncthreads();
    if (tdx == 0) {
        // a2: softmax over ring means
        float ring[4] = {0.f, 0.f, 0.f, 0.f};
        for (int i = 0; i < 9; ++i)
            for (int j = 0; j < 9; ++j) {
                int d = max(abs(i - 4), abs(j - 4));
                int r = (d <= 1) ? 0 : (d - 1);
                ring[r] += tapsum[i * 9 + j];
            }
        float den2[4] = {576.f, 1024.f, 1536.f, 2048.f};   // 64*{9,16,24,32}
        float v[4], mx = -1e30f;
        for (int p = 0; p < 4; ++p) { v[p] = ring[p] / den2[p]; mx = fmaxf(mx, v[p]); }
        float se = 0.f;
        for (int p = 0; p < 4; ++p) { v[p] = expf(v[p] - mx); se += v[p]; }
        for (int p = 0; p < 4; ++p) a2s[p] = v[p] / se;
        // a1
        float k1[9];
        for (int k = 0; k < 9; ++k) k1[k] = W1[k];
        float num[4];
        num[0] = k1[3] + k1[4] + k1[5];
        num[1] = k1[2] + k1[6];
        num[2] = k1[1] + k1[7];
        num[3] = k1[0] + k1[8];
        float den1[4] = {3.f, 2.f, 2.f, 2.f};
        mx = -1e30f;
        for (int p = 0; p < 4; ++p) { v[p] = num[p] / den1[p]; mx = fmaxf(mx, v[p]); }
        se = 0.f;
        for (int p = 0; p < 4; ++p) { v[p] = expf(v[p] - mx); se += v[p]; }
        float a1[4];
        for (int p = 0; p < 4; ++p) a1[p] = v[p] / se;
        // s1(d): d<=1 -> 1 ; d=2 -> a1[1]+a1[2]+a1[3] ; d=3 -> a1[2]+a1[3] ; d=4 -> a1[3]
        float s1arr[5];
        s1arr[0] = 1.f; s1arr[1] = 1.f;
        s1arr[4] = a1[3]; s1arr[3] = a1[2] + a1[3]; s1arr[2] = a1[1] + s1arr[3];
        for (int k = 0; k < 9; ++k) { int d = abs(k - 4); k1e[k] = k1[k] * s1arr[d]; }
    }
    __syncthreads();
    float s2arr[5];
    s2arr[0] = 1.f; s2arr[1] = 1.f;
    s2arr[4] = a2s[3]; s2arr[3] = a2s[2] + a2s[3]; s2arr[2] = a2s[1] + s2arr[3];
    for (int idx = tdx; idx < 64 * 81; idx += 128) {
        int tap = idx % 81;
        int i = tap / 9, j = tap - i * 9;
        int d = max(abs(i - 4), abs(j - 4));
        w2e[idx] = W2[idx] * s2arr[d];
    }
}

// ---------------------------------------------------------------------------
// K1: conv1 (1x1, 256->64) + bias -> h1_raw ; accumulate GN1 sums
// grid 1024 x 256 ; each thread owns one (b,p), all 64 outputs in regs
// ---------------------------------------------------------------------------
__global__ __launch_bounds__(256) void k_conv1(const float* __restrict__ x,
        const float* __restrict__ w1, const float* __restrict__ b1,
        float* __restrict__ h1, float* __restrict__ gn1a) {
    int idx = blockIdx.x * 256 + threadIdx.x;
    int b = idx >> 14, p = idx & 16383;
    const float* xb = x + b * CHW + p;
    float acc[64];
#pragma unroll
    for (int o = 0; o < 64; ++o) acc[o] = b1[o];
#pragma unroll 1
    for (int ci = 0; ci < 256; ci += 4) {
        float x0 = xb[(ci + 0) * HW];
        float x1 = xb[(ci + 1) * HW];
        float x2 = xb[(ci + 2) * HW];
        float x3 = xb[(ci + 3) * HW];
#pragma unroll
        for (int o = 0; o < 64; ++o) {
            const float* wr = w1 + o * 256 + ci;
            float a = acc[o];
            a = fmaf(x0, wr[0], a);
            a = fmaf(x1, wr[1], a);
            a = fmaf(x2, wr[2], a);
            a = fmaf(x3, wr[3], a);
            acc[o] = a;
        }
    }
    float* hb = h1 + b * cHW + p;
#pragma unroll
    for (int o = 0; o < 64; ++o) hb[o * HW] = acc[o];
    // GN1 stats: group g = ch>>2 (16 groups)
    __shared__ float red_s[4][16], red_ss[4][16];
    int lane = threadIdx.x & 63, wv = threadIdx.x >> 6;
#pragma unroll
    for (int g = 0; g < 16; ++g) {
        float a0 = acc[4 * g], a1v = acc[4 * g + 1], a2v = acc[4 * g + 2], a3 = acc[4 * g + 3];
        float s = a0 + a1v + a2v + a3;
        float ss = a0 * a0 + a1v * a1v + a2v * a2v + a3 * a3;
#pragma unroll
        for (int off = 32; off; off >>= 1) { s += __shfl_xor(s, off, 64); ss += __shfl_xor(ss, off, 64); }
        if (lane == 0) { red_s[wv][g] = s; red_ss[wv][g] = ss; }
    }
    __syncthreads();
    if (threadIdx.x < 16) {
        int g = threadIdx.x;
        float s = red_s[0][g] + red_s[1][g] + red_s[2][g] + red_s[3][g];
        float ss = red_ss[0][g] + red_ss[1][g] + red_ss[2][g] + red_ss[3][g];
        atomicAdd(&gn1a[(b * 16 + g) * 2], s);
        atomicAdd(&gn1a[(b * 16 + g) * 2 + 1], ss);
    }
}

// ---------------------------------------------------------------------------
// GN finalize: accum -> per-(b,ch) scale/shift
// ---------------------------------------------------------------------------
__global__ void k_gnfin(const float* __restrict__ accum, const float* __restrict__ gw,
                        const float* __restrict__ gb, float* __restrict__ scale,
                        float* __restrict__ shift, int nent, int chbits, int gshift,
                        float inv_n) {
    int idx = blockIdx.x * blockDim.x + threadIdx.x;
    if (idx >= nent) return;
    int chm = (1 << chbits) - 1;
    int ch = idx & chm, b = idx >> chbits, g = ch >> gshift;
    float s = accum[(b * 16 + g) * 2], ss = accum[(b * 16 + g) * 2 + 1];
    float mu = s * inv_n;
    float var = ss * inv_n - mu * mu;
    float rstd = rsqrtf(var + 1e-5f);
    float sc = gw[ch] * rstd;
    scale[idx] = sc;
    shift[idx] = gb[ch] - mu * sc;
}

// ---------------------------------------------------------------------------
// K3: channel-dim 9-tap conv (pad 4) of normalized h1 -> t
// rolling 9-register window: every h1 element read exactly once
// ---------------------------------------------------------------------------
__global__ __launch_bounds__(256) void k_x3(const float* __restrict__ h1,
        const float* __restrict__ scale1, const float* __restrict__ shift1,
        const float* __restrict__ k1e, float* __restrict__ t) {
    int idx = blockIdx.x * 256 + threadIdx.x;
    int b = idx >> 14, p = idx & 16383;
    const float* hb = h1 + b * cHW + p;
    const float* sc = scale1 + b * 64;
    const float* sh = shift1 + b * 64;
    float ke[9];
#pragma unroll
    for (int k = 0; k < 9; ++k) ke[k] = k1e[k];
    float win[9];
#pragma unroll
    for (int k = 0; k < 9; ++k) {
        int ch = k - 4;
        win[k] = (ch >= 0) ? fmaf(hb[ch * HW], sc[ch], sh[ch]) : 0.f;
    }
    float* tb = t + b * cHW + p;
#pragma unroll
    for (int ch = 0; ch < 64; ++ch) {
        float s = 0.f;
#pragma unroll
        for (int k = 0; k < 9; ++k) s = fmaf(win[k], ke[k], s);
        tb[ch * HW] = s;
#pragma unroll
        for (int k = 0; k < 8; ++k) win[k] = win[k + 1];
        int nc = ch + 5;
        win[8] = (nc < 64) ? fmaf(hb[nc * HW], sc[nc], sh[nc]) : 0.f;
    }
}

// ---------------------------------------------------------------------------
// K4: depthwise 9x9 spatial conv of normalized h1 ; t += x_sa ; GN_s sums
// block = (b, ch, row-tile of 16) ; LDS tile 24 x 136
// ---------------------------------------------------------------------------
__global__ __launch_bounds__(256) void k_xsa(const float* __restrict__ h1,
        const float* __restrict__ scale1, const float* __restrict__ shift1,
        const float* __restrict__ w2e, float* __restrict__ t, float* __restrict__ gnsa) {
    int bid = blockIdx.x;
    int b = bid >> 9, ch = (bid >> 3) & 63, rt = bid & 7;
    int r0 = rt * 16;
    const float sc = scale1[b * 64 + ch];
    const float sh = shift1[b * 64 + ch];
    const float* hp = h1 + b * cHW + ch * HW;
    __shared__ float tile[24 * 136];
    for (int li = threadIdx.x; li < 24 * 136; li += 256) {
        int row = li / 136, col = li - row * 136;
        int gr = r0 - 4 + row, gc = col - 4;
        float v = 0.f;
        if (gr >= 0 && gr < 128 && gc >= 0 && gc < 128)
            v = fmaf(hp[gr * 128 + gc], sc, sh);
        tile[li] = v;
    }
    __syncthreads();
    int q = threadIdx.x & 15, orow = threadIdx.x >> 4;
    const float* wch = w2e + ch * 81;
    float acc[2][4] = {{0.f, 0.f, 0.f, 0.f}, {0.f, 0.f, 0.f, 0.f}};
#pragma unroll
    for (int i = 0; i < 9; ++i) {
#pragma unroll
        for (int m = 0; m < 2; ++m) {
            int c0 = q * 4 + m * 64;
            const float* lr = &tile[(orow + i) * 136 + c0];
            float v[12];
            *(float4*)&v[0] = *(const float4*)lr;
            *(float4*)&v[4] = *(const float4*)(lr + 4);
            *(float4*)&v[8] = *(const float4*)(lr + 8);
#pragma unroll
            for (int j = 0; j < 9; ++j) {
                float wv = wch[i * 9 + j];
                acc[m][0] = fmaf(v[j], wv, acc[m][0]);
                acc[m][1] = fmaf(v[j + 1], wv, acc[m][1]);
                acc[m][2] = fmaf(v[j + 2], wv, acc[m][2]);
                acc[m][3] = fmaf(v[j + 3], wv, acc[m][3]);
            }
        }
    }
    float s = 0.f, ss = 0.f;
    float* tp = t + b * cHW + ch * HW + (r0 + orow) * 128;
#pragma unroll
    for (int m = 0; m < 2; ++m) {
        int c0 = q * 4 + m * 64;
        float4 tv = *(float4*)(tp + c0);
        float r0v = tv.x + acc[m][0];
        float r1v = tv.y + acc[m][1];
        float r2v = tv.z + acc[m][2];
        float r3v = tv.w + acc[m][3];
        float4 rv = make_float4(r0v, r1v, r2v, r3v);
        *(float4*)(tp + c0) = rv;
        s += r0v + r1v + r2v + r3v;
        ss += r0v * r0v + r1v * r1v + r2v * r2v + r3v * r3v;
    }
#pragma unroll
    for (int off = 32; off; off >>= 1) { s += __shfl_xor(s, off, 64); ss += __shfl_xor(ss, off, 64); }
    __shared__ float rs[4], rss[4];
    int lane = threadIdx.x & 63, wv2 = threadIdx.x >> 6;
    if (lane == 0) { rs[wv2] = s; rss[wv2] = ss; }
    __syncthreads();
    if (threadIdx.x == 0) {
        int gi = (b * 16 + (ch >> 2)) * 2;
        atomicAdd(&gnsa[gi], rs[0] + rs[1] + rs[2] + rs[3]);
        atomicAdd(&gnsa[gi + 1], rss[0] + rss[1] + rss[2] + rss[3]);
    }
}

// ---------------------------------------------------------------------------
// K6: h = relu(GN_s(t)) on the fly ; conv2 (1x1, 64->256) + bias -> d_out ;
//     accumulate GN2 sums.  block = (b, 64 positions); 4 o-teams of 64.
// ---------------------------------------------------------------------------
__global__ __launch_bounds__(256) void k_conv2(const float* __restrict__ t,
        const float* __restrict__ scs, const float* __restrict__ shs,
        const float* __restrict__ w2, const float* __restrict__ b2,
        float* __restrict__ out, float* __restrict__ gn2a) {
    int bid = blockIdx.x;
    int b = bid >> 8, p0 = (bid & 255) * 64;
    __shared__ float hsm[64 * 64];
    const float* tb = t + b * cHW + p0;
#pragma unroll 1
    for (int i = 0; i < 16; ++i) {
        int e = i * 256 + threadIdx.x;
        int ch = e >> 6, pl = e & 63;
        float v = tb[ch * HW + pl];
        v = fmaxf(fmaf(v, scs[b * 64 + ch], shs[b * 64 + ch]), 0.f);
        hsm[ch * 64 + pl] = v;
    }
    __syncthreads();
    int team = threadIdx.x >> 6, pl = threadIdx.x & 63;
    int o0 = team * 64;
    float acc[64];
#pragma unroll
    for (int o = 0; o < 64; ++o) acc[o] = b2[o0 + o];
#pragma unroll 1
    for (int ch = 0; ch < 64; ch += 4) {
        float h0 = hsm[(ch + 0) * 64 + pl];
        float h1v = hsm[(ch + 1) * 64 + pl];
        float h2 = hsm[(ch + 2) * 64 + pl];
        float h3 = hsm[(ch + 3) * 64 + pl];
#pragma unroll
        for (int o = 0; o < 64; ++o) {
            const float* wr = w2 + (o0 + o) * 64 + ch;
            float a = acc[o];
            a = fmaf(h0, wr[0], a);
            a = fmaf(h1v, wr[1], a);
            a = fmaf(h2, wr[2], a);
            a = fmaf(h3, wr[3], a);
            acc[o] = a;
        }
    }
    float* ob = out + b * CHW + p0 + pl;
#pragma unroll
    for (int o = 0; o < 64; ++o) ob[(o0 + o) * HW] = acc[o];
    // GN2 stats: wave covers o-range [o0,o0+64) -> 4 groups of 16
    __shared__ float red_s[4][4], red_ss[4][4];
#pragma unroll
    for (int gi = 0; gi < 4; ++gi) {
        float s = 0.f, ss = 0.f;
#pragma unroll
        for (int k = 0; k < 16; ++k) {
            float a = acc[gi * 16 + k];
            s += a; ss += a * a;
        }
#pragma unroll
        for (int off = 32; off; off >>= 1) { s += __shfl_xor(s, off, 64); ss += __shfl_xor(ss, off, 64); }
        if (pl == 0) { red_s[team][gi] = s; red_ss[team][gi] = ss; }
    }
    __syncthreads();
    if (threadIdx.x < 16) {
        int tm = threadIdx.x >> 2, gi = threadIdx.x & 3;
        int g = tm * 4 + gi;
        atomicAdd(&gn2a[(b * 16 + g) * 2], red_s[tm][gi]);
        atomicAdd(&gn2a[(b * 16 + g) * 2 + 1], red_ss[tm][gi]);
    }
}

// ---------------------------------------------------------------------------
// K8: out = relu(GN2(out_raw)) + x   (in-place on d_out, float4)
// ---------------------------------------------------------------------------
__global__ __launch_bounds__(256) void k_final(const float* __restrict__ x,
        const float* __restrict__ sc2, const float* __restrict__ sh2,
        float* __restrict__ out) {
    int tid = blockIdx.x * blockDim.x + threadIdx.x;
    const int total4 = (BB * CHW) / 4;
    int stride = gridDim.x * blockDim.x;
    for (int i = tid; i < total4; i += stride) {
        int e = i * 4;
        int b = e >> 22;
        int o = (e >> 14) & 255;
        float s = sc2[b * 256 + o], h = sh2[b * 256 + o];
        float4 v = ((const float4*)out)[i];
        float4 xv = ((const float4*)x)[i];
        float4 r;
        r.x = fmaxf(fmaf(v.x, s, h), 0.f) + xv.x;
        r.y = fmaxf(fmaf(v.y, s, h), 0.f) + xv.y;
        r.z = fmaxf(fmaf(v.z, s, h), 0.f) + xv.z;
        r.w = fmaxf(fmaf(v.w, s, h), 0.f) + xv.w;
        ((float4*)out)[i] = r;
    }
}

// ---------------------------------------------------------------------------
extern "C" void kernel_launch(void* const* d_in, const int* in_sizes, int n_in,
                              void* d_out, int out_size, void* d_ws, size_t ws_size,
                              hipStream_t stream) {
    (void)in_sizes; (void)n_in; (void)out_size; (void)ws_size;
    const float* x   = (const float*)d_in[0];
    const float* W1  = (const float*)d_in[1];
    const float* W2  = (const float*)d_in[2];
    const float* c1w = (const float*)d_in[3];
    const float* c1b = (const float*)d_in[4];
    const float* c2w = (const float*)d_in[5];
    const float* c2b = (const float*)d_in[6];
    const float* g1w = (const float*)d_in[7];
    const float* g1b = (const float*)d_in[8];
    const float* gsw = (const float*)d_in[9];
    const float* gsb = (const float*)d_in[10];
    const float* g2w = (const float*)d_in[11];
    const float* g2b = (const float*)d_in[12];
    float* out = (float*)d_out;
    float* ws  = (float*)d_ws;

    float* t    = ws + WS_T;
    float* w2e  = ws + WS_W2E;
    float* k1e  = ws + WS_K1E;
    float* gn1a = ws + WS_GN1A;
    float* gnsa = ws + WS_GNSA;
    float* gn2a = ws + WS_GN2A;
    float* sc1  = ws + WS_SC1;
    float* sh1  = ws + WS_SH1;
    float* scs  = ws + WS_SCS;
    float* shs  = ws + WS_SHS;
    float* sc2  = ws + WS_SC2;
    float* sh2  = ws + WS_SH2;

    float* h1 = out;   // stash h1_raw (64 MB) in d_out; dead before conv2 overwrites

    k_setup<<<1, 128, 0, stream>>>(W1, W2, k1e, w2e, gn1a);
    k_conv1<<<1024, 256, 0, stream>>>(x, c1w, c1b, h1, gn1a);
    k_gnfin<<<4, 256, 0, stream>>>(gn1a, g1w, g1b, sc1, sh1, 1024, 6, 2, 1.f / 65536.f);
    k_x3<<<1024, 256, 0, stream>>>(h1, sc1, sh1, k1e, t);
    k_xsa<<<8192, 256, 0, stream>>>(h1, sc1, sh1, w2e, t, gnsa);
    k_gnfin<<<4, 256, 0, stream>>>(gnsa, gsw, gsb, scs, shs, 1024, 6, 2, 1.f / 65536.f);
    k_conv2<<<4096, 256, 0, stream>>>(t, scs, shs, c2w, c2b, out, gn2a);
    k_gnfin<<<16, 256, 0, stream>>>(gn2a, g2w, g2b, sc2, sh2, 4096, 8, 4, 1.f / 262144.f);
    k_final<<<2048, 256, 0, stream>>>(x, sc2, sh2, out);
}

// Round 2
// 670.863 us; speedup vs baseline: 1.6603x; 1.6603x over previous
//
#include <hip/hip_runtime.h>
#include <math.h>

// Problem constants
#define HW   16384        // 128*128
#define CC   256
#define cC   64
#define BB   16
#define CHW  (CC*HW)      // 4194304
#define cHW  (cC*HW)      // 1048576

// ws float offsets
#define WS_T    0
#define WS_W2E  16777216
#define WS_K1E  (WS_W2E + 5184)
#define WS_GN1A (WS_K1E + 16)       // 512 floats
#define WS_GNSA (WS_GN1A + 512)
#define WS_GN2A (WS_GNSA + 512)
#define WS_SC1  (WS_GN2A + 512)     // 1024
#define WS_SH1  (WS_SC1 + 1024)
#define WS_SCS  (WS_SH1 + 1024)
#define WS_SHS  (WS_SCS + 1024)
#define WS_SC2  (WS_SHS + 1024)     // 4096
#define WS_SH2  (WS_SC2 + 4096)
#define WS_W1T  (WS_SH2 + 4096)     // 256x64 transposed conv1 weights
#define WS_W2T  (WS_W1T + 16384)    // 64x256 transposed conv2 weights

// ---------------------------------------------------------------------------
// K0: effective kernels k1_eff[9], W2_eff[64*81]; zero GN accum; transpose W
// ---------------------------------------------------------------------------
__global__ void k_setup(const float* __restrict__ W1, const float* __restrict__ W2,
                        const float* __restrict__ c1w, const float* __restrict__ c2w,
                        float* __restrict__ k1e, float* __restrict__ w2e,
                        float* __restrict__ accz, float* __restrict__ w1t,
                        float* __restrict__ w2t) {
    __shared__ float tapsum[81];
    __shared__ float a2s[4];
    int tdx = threadIdx.x;
    for (int i = tdx; i < 1536; i += 128) accz[i] = 0.f;
    // weight transposes: w1t[c][o] (256x64), w2t[c][o] (64x256)
    for (int idx = tdx; idx < 16384; idx += 128) {
        int c = idx >> 6, o = idx & 63;
        w1t[idx] = c1w[o * 256 + c];
    }
    for (int idx = tdx; idx < 16384; idx += 128) {
        int c = idx >> 8, o = idx & 255;
        w2t[idx] = c2w[o * 64 + c];
    }
    if (tdx < 81) {
        float s = 0.f;
        for (int ch = 0; ch < 64; ++ch) s += W2[ch * 81 + tdx];
        tapsum[tdx] = s;
    }
    __syncthreads();
    if (tdx == 0) {
        float ring[4] = {0.f, 0.f, 0.f, 0.f};
        for (int i = 0; i < 9; ++i)
            for (int j = 0; j < 9; ++j) {
                int d = max(abs(i - 4), abs(j - 4));
                int r = (d <= 1) ? 0 : (d - 1);
                ring[r] += tapsum[i * 9 + j];
            }
        float den2[4] = {576.f, 1024.f, 1536.f, 2048.f};
        float v[4], mx = -1e30f;
        for (int p = 0; p < 4; ++p) { v[p] = ring[p] / den2[p]; mx = fmaxf(mx, v[p]); }
        float se = 0.f;
        for (int p = 0; p < 4; ++p) { v[p] = expf(v[p] - mx); se += v[p]; }
        for (int p = 0; p < 4; ++p) a2s[p] = v[p] / se;
        float k1[9];
        for (int k = 0; k < 9; ++k) k1[k] = W1[k];
        float num[4];
        num[0] = k1[3] + k1[4] + k1[5];
        num[1] = k1[2] + k1[6];
        num[2] = k1[1] + k1[7];
        num[3] = k1[0] + k1[8];
        float den1[4] = {3.f, 2.f, 2.f, 2.f};
        mx = -1e30f;
        for (int p = 0; p < 4; ++p) { v[p] = num[p] / den1[p]; mx = fmaxf(mx, v[p]); }
        se = 0.f;
        for (int p = 0; p < 4; ++p) { v[p] = expf(v[p] - mx); se += v[p]; }
        float a1[4];
        for (int p = 0; p < 4; ++p) a1[p] = v[p] / se;
        float s1arr[5];
        s1arr[0] = 1.f; s1arr[1] = 1.f;
        s1arr[4] = a1[3]; s1arr[3] = a1[2] + a1[3]; s1arr[2] = a1[1] + s1arr[3];
        for (int k = 0; k < 9; ++k) { int d = abs(k - 4); k1e[k] = k1[k] * s1arr[d]; }
    }
    __syncthreads();
    float s2arr[5];
    s2arr[0] = 1.f; s2arr[1] = 1.f;
    s2arr[4] = a2s[3]; s2arr[3] = a2s[2] + a2s[3]; s2arr[2] = a2s[1] + s2arr[3];
    for (int idx = tdx; idx < 64 * 81; idx += 128) {
        int tap = idx % 81;
        int i = tap / 9, j = tap - i * 9;
        int d = max(abs(i - 4), abs(j - 4));
        w2e[idx] = W2[idx] * s2arr[d];
    }
}

// ---------------------------------------------------------------------------
// K1: conv1 (1x1, 256->64) + bias -> h1_raw ; GN1 sums
// block = 128 pos x 64 oc ; thread = 4 pos x 8 oc (acc[8][4]) ; K tiled by 32
// ---------------------------------------------------------------------------
__global__ __launch_bounds__(256) void k_conv1(const float* __restrict__ x,
        const float* __restrict__ w1t, const float* __restrict__ b1,
        float* __restrict__ h1, float* __restrict__ gn1a) {
    int bid = blockIdx.x;
    int b = bid >> 7, pb = bid & 127;
    int p0 = pb * 128;
    int tid = threadIdx.x;
    int po = tid >> 3, oo = tid & 7;           // po 0..31, oo 0..7
    __shared__ float xs[32][128];              // 16 KB
    __shared__ float wsm[32][64];              // 8 KB
    __shared__ float red[4][8][4];
    const float* xb = x + b * CHW + p0;
    float breg[8];
#pragma unroll
    for (int j = 0; j < 8; ++j) breg[j] = b1[oo * 8 + j];
    float acc[8][4];
#pragma unroll
    for (int j = 0; j < 8; ++j)
#pragma unroll
        for (int i = 0; i < 4; ++i) acc[j][i] = 0.f;
#pragma unroll 1
    for (int kt = 0; kt < 8; ++kt) {
        int c0 = kt * 32;
        __syncthreads();
        // stage x tile [32 ch][128 pos]
#pragma unroll
        for (int i = 0; i < 4; ++i) {
            int flat = (i * 256 + tid) * 4;
            int row = flat >> 7, col = flat & 127;
            float4 v = *(const float4*)(xb + (c0 + row) * HW + col);
            *(float4*)&xs[row][col] = v;
        }
        // stage w tile [32 ch][64 oc] from pre-transposed w1t
#pragma unroll
        for (int i = 0; i < 2; ++i) {
            int flat = (i * 256 + tid) * 4;
            int row = flat >> 6, col = flat & 63;
            float4 v = *(const float4*)(w1t + (c0 + row) * 64 + col);
            *(float4*)&wsm[row][col] = v;
        }
        __syncthreads();
#pragma unroll 8
        for (int k = 0; k < 32; ++k) {
            float4 xv = *(const float4*)&xs[k][po * 4];
            float4 wa = *(const float4*)&wsm[k][oo * 8];
            float4 wb = *(const float4*)&wsm[k][oo * 8 + 4];
            float xr[4] = {xv.x, xv.y, xv.z, xv.w};
            float wr[8] = {wa.x, wa.y, wa.z, wa.w, wb.x, wb.y, wb.z, wb.w};
#pragma unroll
            for (int j = 0; j < 8; ++j)
#pragma unroll
                for (int i = 0; i < 4; ++i)
                    acc[j][i] = fmaf(wr[j], xr[i], acc[j][i]);
        }
    }
    // bias + store + stats
    float sA = 0.f, ssA = 0.f, sB = 0.f, ssB = 0.f;
    float* hb = h1 + b * cHW + p0 + po * 4;
#pragma unroll
    for (int j = 0; j < 8; ++j) {
        float a0 = acc[j][0] + breg[j];
        float a1v = acc[j][1] + breg[j];
        float a2v = acc[j][2] + breg[j];
        float a3 = acc[j][3] + breg[j];
        *(float4*)(hb + (oo * 8 + j) * HW) = make_float4(a0, a1v, a2v, a3);
        float s = a0 + a1v + a2v + a3;
        float ss = a0 * a0 + a1v * a1v + a2v * a2v + a3 * a3;
        if (j < 4) { sA += s; ssA += ss; } else { sB += s; ssB += ss; }
    }
#pragma unroll
    for (int off = 8; off < 64; off <<= 1) {
        sA += __shfl_xor(sA, off, 64); ssA += __shfl_xor(ssA, off, 64);
        sB += __shfl_xor(sB, off, 64); ssB += __shfl_xor(ssB, off, 64);
    }
    int lane = tid & 63, wv = tid >> 6;
    if (lane < 8) {
        red[wv][lane][0] = sA; red[wv][lane][1] = ssA;
        red[wv][lane][2] = sB; red[wv][lane][3] = ssB;
    }
    __syncthreads();
    if (tid < 32) {
        int o2 = tid >> 2, c = tid & 3;
        float v = red[0][o2][c] + red[1][o2][c] + red[2][o2][c] + red[3][o2][c];
        int g = o2 * 2 + (c >> 1);
        atomicAdd(&gn1a[(b * 16 + g) * 2 + (c & 1)], v);
    }
}

// ---------------------------------------------------------------------------
// GN finalize: accum -> per-(b,ch) scale/shift
// ---------------------------------------------------------------------------
__global__ void k_gnfin(const float* __restrict__ accum, const float* __restrict__ gw,
                        const float* __restrict__ gb, float* __restrict__ scale,
                        float* __restrict__ shift, int nent, int chbits, int gshift,
                        float inv_n) {
    int idx = blockIdx.x * blockDim.x + threadIdx.x;
    if (idx >= nent) return;
    int chm = (1 << chbits) - 1;
    int ch = idx & chm, b = idx >> chbits, g = ch >> gshift;
    float s = accum[(b * 16 + g) * 2], ss = accum[(b * 16 + g) * 2 + 1];
    float mu = s * inv_n;
    float var = ss * inv_n - mu * mu;
    float rstd = rsqrtf(var + 1e-5f);
    float sc = gw[ch] * rstd;
    scale[idx] = sc;
    shift[idx] = gb[ch] - mu * sc;
}

// ---------------------------------------------------------------------------
// K3: channel-dim 9-tap conv (pad 4) of normalized h1 -> t
// ---------------------------------------------------------------------------
__global__ __launch_bounds__(256) void k_x3(const float* __restrict__ h1,
        const float* __restrict__ scale1, const float* __restrict__ shift1,
        const float* __restrict__ k1e, float* __restrict__ t) {
    int idx = blockIdx.x * 256 + threadIdx.x;
    int b = idx >> 14, p = idx & 16383;
    const float* hb = h1 + b * cHW + p;
    const float* sc = scale1 + b * 64;
    const float* sh = shift1 + b * 64;
    float ke[9];
#pragma unroll
    for (int k = 0; k < 9; ++k) ke[k] = k1e[k];
    float win[9];
#pragma unroll
    for (int k = 0; k < 9; ++k) {
        int ch = k - 4;
        win[k] = (ch >= 0) ? fmaf(hb[ch * HW], sc[ch], sh[ch]) : 0.f;
    }
    float* tb = t + b * cHW + p;
#pragma unroll
    for (int ch = 0; ch < 64; ++ch) {
        float s = 0.f;
#pragma unroll
        for (int k = 0; k < 9; ++k) s = fmaf(win[k], ke[k], s);
        tb[ch * HW] = s;
#pragma unroll
        for (int k = 0; k < 8; ++k) win[k] = win[k + 1];
        int nc = ch + 5;
        win[8] = (nc < 64) ? fmaf(hb[nc * HW], sc[nc], sh[nc]) : 0.f;
    }
}

// ---------------------------------------------------------------------------
// K4: depthwise 9x9 spatial conv ; t += x_sa ; GN_s sums
// ---------------------------------------------------------------------------
__global__ __launch_bounds__(256) void k_xsa(const float* __restrict__ h1,
        const float* __restrict__ scale1, const float* __restrict__ shift1,
        const float* __restrict__ w2e, float* __restrict__ t, float* __restrict__ gnsa) {
    int bid = blockIdx.x;
    int b = bid >> 9, ch = (bid >> 3) & 63, rt = bid & 7;
    int r0 = rt * 16;
    const float sc = scale1[b * 64 + ch];
    const float sh = shift1[b * 64 + ch];
    const float* hp = h1 + b * cHW + ch * HW;
    __shared__ float tile[24 * 136];
    for (int li = threadIdx.x; li < 24 * 136; li += 256) {
        int row = li / 136, col = li - row * 136;
        int gr = r0 - 4 + row, gc = col - 4;
        float v = 0.f;
        if (gr >= 0 && gr < 128 && gc >= 0 && gc < 128)
            v = fmaf(hp[gr * 128 + gc], sc, sh);
        tile[li] = v;
    }
    __syncthreads();
    int q = threadIdx.x & 15, orow = threadIdx.x >> 4;
    const float* wch = w2e + ch * 81;
    float acc[2][4] = {{0.f, 0.f, 0.f, 0.f}, {0.f, 0.f, 0.f, 0.f}};
#pragma unroll
    for (int i = 0; i < 9; ++i) {
#pragma unroll
        for (int m = 0; m < 2; ++m) {
            int c0 = q * 4 + m * 64;
            const float* lr = &tile[(orow + i) * 136 + c0];
            float v[12];
            *(float4*)&v[0] = *(const float4*)lr;
            *(float4*)&v[4] = *(const float4*)(lr + 4);
            *(float4*)&v[8] = *(const float4*)(lr + 8);
#pragma unroll
            for (int j = 0; j < 9; ++j) {
                float wv = wch[i * 9 + j];
                acc[m][0] = fmaf(v[j], wv, acc[m][0]);
                acc[m][1] = fmaf(v[j + 1], wv, acc[m][1]);
                acc[m][2] = fmaf(v[j + 2], wv, acc[m][2]);
                acc[m][3] = fmaf(v[j + 3], wv, acc[m][3]);
            }
        }
    }
    float s = 0.f, ss = 0.f;
    float* tp = t + b * cHW + ch * HW + (r0 + orow) * 128;
#pragma unroll
    for (int m = 0; m < 2; ++m) {
        int c0 = q * 4 + m * 64;
        float4 tv = *(float4*)(tp + c0);
        float r0v = tv.x + acc[m][0];
        float r1v = tv.y + acc[m][1];
        float r2v = tv.z + acc[m][2];
        float r3v = tv.w + acc[m][3];
        *(float4*)(tp + c0) = make_float4(r0v, r1v, r2v, r3v);
        s += r0v + r1v + r2v + r3v;
        ss += r0v * r0v + r1v * r1v + r2v * r2v + r3v * r3v;
    }
#pragma unroll
    for (int off = 32; off; off >>= 1) { s += __shfl_xor(s, off, 64); ss += __shfl_xor(ss, off, 64); }
    __shared__ float rs[4], rss[4];
    int lane = threadIdx.x & 63, wv2 = threadIdx.x >> 6;
    if (lane == 0) { rs[wv2] = s; rss[wv2] = ss; }
    __syncthreads();
    if (threadIdx.x == 0) {
        int gi = (b * 16 + (ch >> 2)) * 2;
        atomicAdd(&gnsa[gi], rs[0] + rs[1] + rs[2] + rs[3]);
        atomicAdd(&gnsa[gi + 1], rss[0] + rss[1] + rss[2] + rss[3]);
    }
}

// ---------------------------------------------------------------------------
// K6: conv2 (1x1, 64->256) with relu(GN_s(t)) applied at staging ; GN2 sums
// block = 128 pos x 64 oc (obk of 4) ; thread = 4 pos x 8 oc ; K=64 tiled by 32
// ---------------------------------------------------------------------------
__global__ __launch_bounds__(256) void k_conv2(const float* __restrict__ t,
        const float* __restrict__ scs, const float* __restrict__ shs,
        const float* __restrict__ w2t, const float* __restrict__ b2,
        float* __restrict__ out, float* __restrict__ gn2a) {
    int bid = blockIdx.x;
    int obk = bid & 3, pb = (bid >> 2) & 127, b = bid >> 9;
    int p0 = pb * 128;
    int tid = threadIdx.x;
    int po = tid >> 3, oo = tid & 7;
    __shared__ float hs[32][128];              // 16 KB
    __shared__ float wsm[32][64];              // 8 KB
    __shared__ float red[4][8][2];
    const float* tb = t + b * cHW + p0;
    const float* scb = scs + b * 64;
    const float* shb = shs + b * 64;
    float breg[8];
#pragma unroll
    for (int j = 0; j < 8; ++j) breg[j] = b2[obk * 64 + oo * 8 + j];
    float acc[8][4];
#pragma unroll
    for (int j = 0; j < 8; ++j)
#pragma unroll
        for (int i = 0; i < 4; ++i) acc[j][i] = 0.f;
#pragma unroll 1
    for (int kt = 0; kt < 2; ++kt) {
        int c0 = kt * 32;
        __syncthreads();
        // stage normalized+relu'd t tile [32 ch][128 pos]
#pragma unroll
        for (int i = 0; i < 4; ++i) {
            int flat = (i * 256 + tid) * 4;
            int row = flat >> 7, col = flat & 127;
            int ch = c0 + row;
            float s = scb[ch], h = shb[ch];
            float4 v = *(const float4*)(tb + ch * HW + col);
            v.x = fmaxf(fmaf(v.x, s, h), 0.f);
            v.y = fmaxf(fmaf(v.y, s, h), 0.f);
            v.z = fmaxf(fmaf(v.z, s, h), 0.f);
            v.w = fmaxf(fmaf(v.w, s, h), 0.f);
            *(float4*)&hs[row][col] = v;
        }
        // stage w tile [32 ch][64 oc] from pre-transposed w2t
#pragma unroll
        for (int i = 0; i < 2; ++i) {
            int flat = (i * 256 + tid) * 4;
            int row = flat >> 6, col = flat & 63;
            float4 v = *(const float4*)(w2t + (c0 + row) * 256 + obk * 64 + col);
            *(float4*)&wsm[row][col] = v;
        }
        __syncthreads();
#pragma unroll 8
        for (int k = 0; k < 32; ++k) {
            float4 xv = *(const float4*)&hs[k][po * 4];
            float4 wa = *(const float4*)&wsm[k][oo * 8];
            float4 wb = *(const float4*)&wsm[k][oo * 8 + 4];
            float xr[4] = {xv.x, xv.y, xv.z, xv.w};
            float wr[8] = {wa.x, wa.y, wa.z, wa.w, wb.x, wb.y, wb.z, wb.w};
#pragma unroll
            for (int j = 0; j < 8; ++j)
#pragma unroll
                for (int i = 0; i < 4; ++i)
                    acc[j][i] = fmaf(wr[j], xr[i], acc[j][i]);
        }
    }
    // bias + store + GN2 stats (thread covers single group g = obk*4 + oo/2)
    float sg = 0.f, ssg = 0.f;
    float* ob = out + b * CHW + (obk * 64) * HW + p0 + po * 4;
#pragma unroll
    for (int j = 0; j < 8; ++j) {
        float a0 = acc[j][0] + breg[j];
        float a1v = acc[j][1] + breg[j];
        float a2v = acc[j][2] + breg[j];
        float a3 = acc[j][3] + breg[j];
        *(float4*)(ob + (oo * 8 + j) * HW) = make_float4(a0, a1v, a2v, a3);
        sg += a0 + a1v + a2v + a3;
        ssg += a0 * a0 + a1v * a1v + a2v * a2v + a3 * a3;
    }
#pragma unroll
    for (int off = 8; off < 64; off <<= 1) {
        sg += __shfl_xor(sg, off, 64); ssg += __shfl_xor(ssg, off, 64);
    }
    int lane = tid & 63, wv = tid >> 6;
    if (lane < 8) { red[wv][lane][0] = sg; red[wv][lane][1] = ssg; }
    __syncthreads();
    if (tid < 16) {
        int o2 = tid >> 1, c = tid & 1;
        float v = red[0][o2][c] + red[1][o2][c] + red[2][o2][c] + red[3][o2][c];
        int g = obk * 4 + (o2 >> 1);
        atomicAdd(&gn2a[(b * 16 + g) * 2 + c], v);
    }
}

// ---------------------------------------------------------------------------
// K8: out = relu(GN2(out_raw)) + x   (in-place on d_out, float4)
// ---------------------------------------------------------------------------
__global__ __launch_bounds__(256) void k_final(const float* __restrict__ x,
        const float* __restrict__ sc2, const float* __restrict__ sh2,
        float* __restrict__ out) {
    int tid = blockIdx.x * blockDim.x + threadIdx.x;
    const int total4 = (BB * CHW) / 4;
    int stride = gridDim.x * blockDim.x;
    for (int i = tid; i < total4; i += stride) {
        int e = i * 4;
        int b = e >> 22;
        int o = (e >> 14) & 255;
        float s = sc2[b * 256 + o], h = sh2[b * 256 + o];
        float4 v = ((const float4*)out)[i];
        float4 xv = ((const float4*)x)[i];
        float4 r;
        r.x = fmaxf(fmaf(v.x, s, h), 0.f) + xv.x;
        r.y = fmaxf(fmaf(v.y, s, h), 0.f) + xv.y;
        r.z = fmaxf(fmaf(v.z, s, h), 0.f) + xv.z;
        r.w = fmaxf(fmaf(v.w, s, h), 0.f) + xv.w;
        ((float4*)out)[i] = r;
    }
}

// ---------------------------------------------------------------------------
extern "C" void kernel_launch(void* const* d_in, const int* in_sizes, int n_in,
                              void* d_out, int out_size, void* d_ws, size_t ws_size,
                              hipStream_t stream) {
    (void)in_sizes; (void)n_in; (void)out_size; (void)ws_size;
    const float* x   = (const float*)d_in[0];
    const float* W1  = (const float*)d_in[1];
    const float* W2  = (const float*)d_in[2];
    const float* c1w = (const float*)d_in[3];
    const float* c1b = (const float*)d_in[4];
    const float* c2w = (const float*)d_in[5];
    const float* c2b = (const float*)d_in[6];
    const float* g1w = (const float*)d_in[7];
    const float* g1b = (const float*)d_in[8];
    const float* gsw = (const float*)d_in[9];
    const float* gsb = (const float*)d_in[10];
    const float* g2w = (const float*)d_in[11];
    const float* g2b = (const float*)d_in[12];
    float* out = (float*)d_out;
    float* ws  = (float*)d_ws;

    float* t    = ws + WS_T;
    float* w2e  = ws + WS_W2E;
    float* k1e  = ws + WS_K1E;
    float* gn1a = ws + WS_GN1A;
    float* gnsa = ws + WS_GNSA;
    float* gn2a = ws + WS_GN2A;
    float* sc1  = ws + WS_SC1;
    float* sh1  = ws + WS_SH1;
    float* scs  = ws + WS_SCS;
    float* shs  = ws + WS_SHS;
    float* sc2  = ws + WS_SC2;
    float* sh2  = ws + WS_SH2;
    float* w1t  = ws + WS_W1T;
    float* w2t  = ws + WS_W2T;

    float* h1 = out;   // stash h1_raw (64 MB) in d_out; dead before conv2 overwrites

    k_setup<<<1, 128, 0, stream>>>(W1, W2, c1w, c2w, k1e, w2e, gn1a, w1t, w2t);
    k_conv1<<<2048, 256, 0, stream>>>(x, w1t, c1b, h1, gn1a);
    k_gnfin<<<4, 256, 0, stream>>>(gn1a, g1w, g1b, sc1, sh1, 1024, 6, 2, 1.f / 65536.f);
    k_x3<<<1024, 256, 0, stream>>>(h1, sc1, sh1, k1e, t);
    k_xsa<<<8192, 256, 0, stream>>>(h1, sc1, sh1, w2e, t, gnsa);
    k_gnfin<<<4, 256, 0, stream>>>(gnsa, gsw, gsb, scs, shs, 1024, 6, 2, 1.f / 65536.f);
    k_conv2<<<8192, 256, 0, stream>>>(t, scs, shs, w2t, c2b, out, gn2a);
    k_gnfin<<<16, 256, 0, stream>>>(gn2a, g2w, g2b, sc2, sh2, 4096, 8, 4, 1.f / 262144.f);
    k_final<<<2048, 256, 0, stream>>>(x, sc2, sh2, out);
}

// Round 3
// 515.376 us; speedup vs baseline: 2.1612x; 1.3017x over previous
//
#include <hip/hip_runtime.h>
#include <math.h>

// Problem constants
#define HW   16384        // 128*128
#define CC   256
#define cC   64
#define BB   16
#define CHW  (CC*HW)      // 4194304
#define cHW  (cC*HW)      // 1048576

// ws float offsets
#define WS_T    0
#define WS_W2E  16777216
#define WS_K1E  (WS_W2E + 5184)
#define WS_GN1A (WS_K1E + 16)       // 512 floats
#define WS_GNSA (WS_GN1A + 512)
#define WS_GN2A (WS_GNSA + 512)
#define WS_SC1  (WS_GN2A + 512)     // 1024
#define WS_SH1  (WS_SC1 + 1024)
#define WS_SCS  (WS_SH1 + 1024)
#define WS_SHS  (WS_SCS + 1024)
#define WS_SC2  (WS_SHS + 1024)     // 4096
#define WS_SH2  (WS_SC2 + 4096)
#define WS_W1P  (WS_SH2 + 4096)     // 16384 ushort = 8192 floats (MFMA-frag-packed W1)
#define WS_W2P  (WS_W1P + 8192)     // 16384 ushort = 8192 floats (MFMA-frag-packed W2)

typedef __attribute__((ext_vector_type(8))) short bf16x8;
typedef __attribute__((ext_vector_type(4))) float f32x4;

__device__ inline unsigned short f2bf(float f) {
    union { float f; unsigned u; } c; c.f = f;
    unsigned r = c.u + 0x7FFFu + ((c.u >> 16) & 1u);
    return (unsigned short)(r >> 16);
}

// ---------------------------------------------------------------------------
// K0: effective kernels k1_eff[9], W2_eff[64*81]; zero GN accum;
//     pack conv weights into MFMA fragment order (bf16).
// w1p frag fi = ks*4+nf (ks 0..7, nf 0..3): elem [fi*512 + lane*8 + j] =
//   bf16(c1w[(nf*16+(lane&15))*256 + ks*32+(lane>>4)*8+j])
// w2p frag fi = ks*16+nfg (ks 0..1, nfg 0..15): elem = bf16(c2w[oc*64+c])
// ---------------------------------------------------------------------------
__global__ void k_setup(const float* __restrict__ W1, const float* __restrict__ W2,
                        const float* __restrict__ c1w, const float* __restrict__ c2w,
                        float* __restrict__ k1e, float* __restrict__ w2e,
                        float* __restrict__ accz, unsigned short* __restrict__ w1p,
                        unsigned short* __restrict__ w2p) {
    __shared__ float tapsum[81];
    __shared__ float a2s[4];
    int tdx = threadIdx.x;
    for (int i = tdx; i < 1536; i += 128) accz[i] = 0.f;
    // pack W1 fragments
    for (int e = tdx; e < 16384; e += 128) {
        int fi = e >> 9, rem = e & 511;
        int l = rem >> 3, j = rem & 7;
        int ks = fi >> 2, nf = fi & 3;
        int c = ks * 32 + (l >> 4) * 8 + j;
        int oc = nf * 16 + (l & 15);
        w1p[e] = f2bf(c1w[oc * 256 + c]);
    }
    // pack W2 fragments
    for (int e = tdx; e < 16384; e += 128) {
        int fi = e >> 9, rem = e & 511;
        int l = rem >> 3, j = rem & 7;
        int ks = fi >> 4, nfg = fi & 15;
        int c = ks * 32 + (l >> 4) * 8 + j;
        int oc = nfg * 16 + (l & 15);
        w2p[e] = f2bf(c2w[oc * 64 + c]);
    }
    if (tdx < 81) {
        float s = 0.f;
        for (int ch = 0; ch < 64; ++ch) s += W2[ch * 81 + tdx];
        tapsum[tdx] = s;
    }
    __syncthreads();
    if (tdx == 0) {
        float ring[4] = {0.f, 0.f, 0.f, 0.f};
        for (int i = 0; i < 9; ++i)
            for (int j = 0; j < 9; ++j) {
                int d = max(abs(i - 4), abs(j - 4));
                int r = (d <= 1) ? 0 : (d - 1);
                ring[r] += tapsum[i * 9 + j];
            }
        float den2[4] = {576.f, 1024.f, 1536.f, 2048.f};
        float v[4], mx = -1e30f;
        for (int p = 0; p < 4; ++p) { v[p] = ring[p] / den2[p]; mx = fmaxf(mx, v[p]); }
        float se = 0.f;
        for (int p = 0; p < 4; ++p) { v[p] = expf(v[p] - mx); se += v[p]; }
        for (int p = 0; p < 4; ++p) a2s[p] = v[p] / se;
        float k1[9];
        for (int k = 0; k < 9; ++k) k1[k] = W1[k];
        float num[4];
        num[0] = k1[3] + k1[4] + k1[5];
        num[1] = k1[2] + k1[6];
        num[2] = k1[1] + k1[7];
        num[3] = k1[0] + k1[8];
        float den1[4] = {3.f, 2.f, 2.f, 2.f};
        mx = -1e30f;
        for (int p = 0; p < 4; ++p) { v[p] = num[p] / den1[p]; mx = fmaxf(mx, v[p]); }
        se = 0.f;
        for (int p = 0; p < 4; ++p) { v[p] = expf(v[p] - mx); se += v[p]; }
        float a1[4];
        for (int p = 0; p < 4; ++p) a1[p] = v[p] / se;
        float s1arr[5];
        s1arr[0] = 1.f; s1arr[1] = 1.f;
        s1arr[4] = a1[3]; s1arr[3] = a1[2] + a1[3]; s1arr[2] = a1[1] + s1arr[3];
        for (int k = 0; k < 9; ++k) { int d = abs(k - 4); k1e[k] = k1[k] * s1arr[d]; }
    }
    __syncthreads();
    float s2arr[5];
    s2arr[0] = 1.f; s2arr[1] = 1.f;
    s2arr[4] = a2s[3]; s2arr[3] = a2s[2] + a2s[3]; s2arr[2] = a2s[1] + s2arr[3];
    for (int idx = tdx; idx < 64 * 81; idx += 128) {
        int tap = idx % 81;
        int i = tap / 9, j = tap - i * 9;
        int d = max(abs(i - 4), abs(j - 4));
        w2e[idx] = W2[idx] * s2arr[d];
    }
}

// ---------------------------------------------------------------------------
// K1: conv1 (1x1, 256->64) via bf16 MFMA -> h1_raw f32 [ch][p] ; GN1 sums
// grid = 16b x 64 ptiles(256 pos) ; 4 waves ; wave = 64 pos x 64 oc
// A-frags: per-lane direct global loads of x (f32->bf16) ; B-frags: w1p packed
// ---------------------------------------------------------------------------
__global__ __launch_bounds__(256) void k_conv1(const float* __restrict__ x,
        const unsigned short* __restrict__ w1p, const float* __restrict__ b1,
        float* __restrict__ h1, float* __restrict__ gn1a) {
    int bid = blockIdx.x;
    int b = bid >> 6, pt = bid & 63;
    int tid = threadIdx.x;
    int w = tid >> 6, lane = tid & 63;
    int l15 = lane & 15, lg = lane >> 4;
    int p_wave = pt * 256 + w * 64;
    const bf16x8* w1v = (const bf16x8*)w1p;
    f32x4 acc[4][4];
#pragma unroll
    for (int mf = 0; mf < 4; ++mf)
#pragma unroll
        for (int nf = 0; nf < 4; ++nf) acc[mf][nf] = (f32x4){0.f, 0.f, 0.f, 0.f};
    const float* xb = x + b * CHW;
#pragma unroll 1
    for (int ks = 0; ks < 8; ++ks) {
        int c0 = ks * 32 + lg * 8;
        bf16x8 afr[4];
#pragma unroll
        for (int mf = 0; mf < 4; ++mf) {
            const float* xp = xb + c0 * HW + p_wave + mf * 16 + l15;
            bf16x8 a;
#pragma unroll
            for (int j = 0; j < 8; ++j) a[j] = (short)f2bf(xp[j * HW]);
            afr[mf] = a;
        }
#pragma unroll
        for (int nf = 0; nf < 4; ++nf) {
            bf16x8 bfr = w1v[(ks * 4 + nf) * 64 + lane];
#pragma unroll
            for (int mf = 0; mf < 4; ++mf)
                acc[mf][nf] = __builtin_amdgcn_mfma_f32_16x16x32_bf16(afr[mf], bfr, acc[mf][nf], 0, 0, 0);
        }
    }
    // epilogue: bias, store f32 [ch][p], GN1 stats
    __shared__ float red[4][16][2];
    float* hb = h1 + b * cHW;
#pragma unroll
    for (int nf = 0; nf < 4; ++nf) {
        int oc = nf * 16 + l15;
        float bias = b1[oc];
        float s = 0.f, ss = 0.f;
#pragma unroll
        for (int mf = 0; mf < 4; ++mf) {
            f32x4 v = acc[mf][nf];
            v[0] += bias; v[1] += bias; v[2] += bias; v[3] += bias;
            *(f32x4*)(hb + oc * HW + p_wave + mf * 16 + lg * 4) = v;
            s += v[0] + v[1] + v[2] + v[3];
            ss += v[0] * v[0] + v[1] * v[1] + v[2] * v[2] + v[3] * v[3];
        }
        // sum over lg (same oc): lanes xor 16,32 ; then over 4 oc of group: xor 1,2
        s += __shfl_xor(s, 16, 64); ss += __shfl_xor(ss, 16, 64);
        s += __shfl_xor(s, 32, 64); ss += __shfl_xor(ss, 32, 64);
        s += __shfl_xor(s, 1, 64);  ss += __shfl_xor(ss, 1, 64);
        s += __shfl_xor(s, 2, 64);  ss += __shfl_xor(ss, 2, 64);
        if (lg == 0 && (l15 & 3) == 0) {
            int g = nf * 4 + (l15 >> 2);
            red[w][g][0] = s; red[w][g][1] = ss;
        }
    }
    __syncthreads();
    if (tid < 32) {
        int g = tid >> 1, c = tid & 1;
        float v = red[0][g][c] + red[1][g][c] + red[2][g][c] + red[3][g][c];
        atomicAdd(&gn1a[(b * 16 + g) * 2 + c], v);
    }
}

// ---------------------------------------------------------------------------
// GN finalize: accum -> per-(b,ch) scale/shift
// ---------------------------------------------------------------------------
__global__ void k_gnfin(const float* __restrict__ accum, const float* __restrict__ gw,
                        const float* __restrict__ gb, float* __restrict__ scale,
                        float* __restrict__ shift, int nent, int chbits, int gshift,
                        float inv_n) {
    int idx = blockIdx.x * blockDim.x + threadIdx.x;
    if (idx >= nent) return;
    int chm = (1 << chbits) - 1;
    int ch = idx & chm, b = idx >> chbits, g = ch >> gshift;
    float s = accum[(b * 16 + g) * 2], ss = accum[(b * 16 + g) * 2 + 1];
    float mu = s * inv_n;
    float var = ss * inv_n - mu * mu;
    float rstd = rsqrtf(var + 1e-5f);
    float sc = gw[ch] * rstd;
    scale[idx] = sc;
    shift[idx] = gb[ch] - mu * sc;
}

// ---------------------------------------------------------------------------
// K3: channel-dim 9-tap conv (pad 4) of normalized h1 -> t
// ---------------------------------------------------------------------------
__global__ __launch_bounds__(256) void k_x3(const float* __restrict__ h1,
        const float* __restrict__ scale1, const float* __restrict__ shift1,
        const float* __restrict__ k1e, float* __restrict__ t) {
    int idx = blockIdx.x * 256 + threadIdx.x;
    int b = idx >> 14, p = idx & 16383;
    const float* hb = h1 + b * cHW + p;
    const float* sc = scale1 + b * 64;
    const float* sh = shift1 + b * 64;
    float ke[9];
#pragma unroll
    for (int k = 0; k < 9; ++k) ke[k] = k1e[k];
    float win[9];
#pragma unroll
    for (int k = 0; k < 9; ++k) {
        int ch = k - 4;
        win[k] = (ch >= 0) ? fmaf(hb[ch * HW], sc[ch], sh[ch]) : 0.f;
    }
    float* tb = t + b * cHW + p;
#pragma unroll
    for (int ch = 0; ch < 64; ++ch) {
        float s = 0.f;
#pragma unroll
        for (int k = 0; k < 9; ++k) s = fmaf(win[k], ke[k], s);
        tb[ch * HW] = s;
#pragma unroll
        for (int k = 0; k < 8; ++k) win[k] = win[k + 1];
        int nc = ch + 5;
        win[8] = (nc < 64) ? fmaf(hb[nc * HW], sc[nc], sh[nc]) : 0.f;
    }
}

// ---------------------------------------------------------------------------
// K4: depthwise 9x9 spatial conv ; t += x_sa ; GN_s sums
// ---------------------------------------------------------------------------
__global__ __launch_bounds__(256) void k_xsa(const float* __restrict__ h1,
        const float* __restrict__ scale1, const float* __restrict__ shift1,
        const float* __restrict__ w2e, float* __restrict__ t, float* __restrict__ gnsa) {
    int bid = blockIdx.x;
    int b = bid >> 9, ch = (bid >> 3) & 63, rt = bid & 7;
    int r0 = rt * 16;
    const float sc = scale1[b * 64 + ch];
    const float sh = shift1[b * 64 + ch];
    const float* hp = h1 + b * cHW + ch * HW;
    __shared__ float tile[24 * 136];
    for (int li = threadIdx.x; li < 24 * 136; li += 256) {
        int row = li / 136, col = li - row * 136;
        int gr = r0 - 4 + row, gc = col - 4;
        float v = 0.f;
        if (gr >= 0 && gr < 128 && gc >= 0 && gc < 128)
            v = fmaf(hp[gr * 128 + gc], sc, sh);
        tile[li] = v;
    }
    __syncthreads();
    int q = threadIdx.x & 15, orow = threadIdx.x >> 4;
    const float* wch = w2e + ch * 81;
    float acc[2][4] = {{0.f, 0.f, 0.f, 0.f}, {0.f, 0.f, 0.f, 0.f}};
#pragma unroll
    for (int i = 0; i < 9; ++i) {
#pragma unroll
        for (int m = 0; m < 2; ++m) {
            int c0 = q * 4 + m * 64;
            const float* lr = &tile[(orow + i) * 136 + c0];
            float v[12];
            *(float4*)&v[0] = *(const float4*)lr;
            *(float4*)&v[4] = *(const float4*)(lr + 4);
            *(float4*)&v[8] = *(const float4*)(lr + 8);
#pragma unroll
            for (int j = 0; j < 9; ++j) {
                float wv = wch[i * 9 + j];
                acc[m][0] = fmaf(v[j], wv, acc[m][0]);
                acc[m][1] = fmaf(v[j + 1], wv, acc[m][1]);
                acc[m][2] = fmaf(v[j + 2], wv, acc[m][2]);
                acc[m][3] = fmaf(v[j + 3], wv, acc[m][3]);
            }
        }
    }
    float s = 0.f, ss = 0.f;
    float* tp = t + b * cHW + ch * HW + (r0 + orow) * 128;
#pragma unroll
    for (int m = 0; m < 2; ++m) {
        int c0 = q * 4 + m * 64;
        float4 tv = *(float4*)(tp + c0);
        float r0v = tv.x + acc[m][0];
        float r1v = tv.y + acc[m][1];
        float r2v = tv.z + acc[m][2];
        float r3v = tv.w + acc[m][3];
        *(float4*)(tp + c0) = make_float4(r0v, r1v, r2v, r3v);
        s += r0v + r1v + r2v + r3v;
        ss += r0v * r0v + r1v * r1v + r2v * r2v + r3v * r3v;
    }
#pragma unroll
    for (int off = 32; off; off >>= 1) { s += __shfl_xor(s, off, 64); ss += __shfl_xor(ss, off, 64); }
    __shared__ float rs[4], rss[4];
    int lane = threadIdx.x & 63, wv2 = threadIdx.x >> 6;
    if (lane == 0) { rs[wv2] = s; rss[wv2] = ss; }
    __syncthreads();
    if (threadIdx.x == 0) {
        int gi = (b * 16 + (ch >> 2)) * 2;
        atomicAdd(&gnsa[gi], rs[0] + rs[1] + rs[2] + rs[3]);
        atomicAdd(&gnsa[gi + 1], rss[0] + rss[1] + rss[2] + rss[3]);
    }
}

// ---------------------------------------------------------------------------
// K6: conv2 (1x1, 64->256) via bf16 MFMA ; relu(GN_s) fused into A-frags ;
// out f32 [ch][p] ; GN2 sums.
// grid = 16b x 128 ptiles(128 pos) x 2 obk ; 4 waves (2 p-halves x 2 oc-cols)
// ---------------------------------------------------------------------------
__global__ __launch_bounds__(256) void k_conv2(const float* __restrict__ t,
        const float* __restrict__ scs, const float* __restrict__ shs,
        const unsigned short* __restrict__ w2p, const float* __restrict__ b2,
        float* __restrict__ out, float* __restrict__ gn2a) {
    int bid = blockIdx.x;
    int obk = bid & 1, pt = (bid >> 1) & 127, b = bid >> 8;
    int tid = threadIdx.x;
    int w = tid >> 6, lane = tid & 63;
    int l15 = lane & 15, lg = lane >> 4;
    int pw = w >> 1, ow = w & 1;
    int p_wave = pt * 128 + pw * 64;
    __shared__ float lsc[64], lsh[64];
    __shared__ float red[4][4][2];
    if (tid < 64) { lsc[tid] = scs[b * 64 + tid]; lsh[tid] = shs[b * 64 + tid]; }
    __syncthreads();
    const bf16x8* w2v = (const bf16x8*)w2p;
    f32x4 acc[4][4];
#pragma unroll
    for (int mf = 0; mf < 4; ++mf)
#pragma unroll
        for (int nf = 0; nf < 4; ++nf) acc[mf][nf] = (f32x4){0.f, 0.f, 0.f, 0.f};
    const float* tb = t + b * cHW;
#pragma unroll
    for (int ks = 0; ks < 2; ++ks) {
        int kb = ks * 32 + lg * 8;
        float kc[8], kh[8];
#pragma unroll
        for (int j = 0; j < 8; ++j) { kc[j] = lsc[kb + j]; kh[j] = lsh[kb + j]; }
        bf16x8 afr[4];
#pragma unroll
        for (int mf = 0; mf < 4; ++mf) {
            const float* tp = tb + kb * HW + p_wave + mf * 16 + l15;
            bf16x8 a;
#pragma unroll
            for (int j = 0; j < 8; ++j) {
                float v = fmaxf(fmaf(tp[j * HW], kc[j], kh[j]), 0.f);
                a[j] = (short)f2bf(v);
            }
            afr[mf] = a;
        }
#pragma unroll
        for (int nf = 0; nf < 4; ++nf) {
            int fi = ks * 16 + (obk * 8 + ow * 4 + nf);
            bf16x8 bfr = w2v[fi * 64 + lane];
#pragma unroll
            for (int mf = 0; mf < 4; ++mf)
                acc[mf][nf] = __builtin_amdgcn_mfma_f32_16x16x32_bf16(afr[mf], bfr, acc[mf][nf], 0, 0, 0);
        }
    }
    // epilogue: bias, store f32 [ch][p], GN2 stats (group = oc>>4)
    int oc0 = obk * 128 + ow * 64;
    float* ob = out + b * CHW;
    float sred[4], ssred[4];
#pragma unroll
    for (int nf = 0; nf < 4; ++nf) {
        int oc = oc0 + nf * 16 + l15;
        float bias = b2[oc];
        float s = 0.f, ss = 0.f;
#pragma unroll
        for (int mf = 0; mf < 4; ++mf) {
            f32x4 v = acc[mf][nf];
            v[0] += bias; v[1] += bias; v[2] += bias; v[3] += bias;
            *(f32x4*)(ob + oc * HW + p_wave + mf * 16 + lg * 4) = v;
            s += v[0] + v[1] + v[2] + v[3];
            ss += v[0] * v[0] + v[1] * v[1] + v[2] * v[2] + v[3] * v[3];
        }
#pragma unroll
        for (int off = 32; off; off >>= 1) { s += __shfl_xor(s, off, 64); ss += __shfl_xor(ss, off, 64); }
        sred[nf] = s; ssred[nf] = ss;
    }
    if (lane == 0) {
#pragma unroll
        for (int nf = 0; nf < 4; ++nf) { red[w][nf][0] = sred[nf]; red[w][nf][1] = ssred[nf]; }
    }
    __syncthreads();
    if (tid < 16) {
        int ow2 = tid >> 3, nf = (tid >> 1) & 3, c = tid & 1;
        float v = red[ow2][nf][c] + red[ow2 + 2][nf][c];
        int g = obk * 8 + ow2 * 4 + nf;
        atomicAdd(&gn2a[(b * 16 + g) * 2 + c], v);
    }
}

// ---------------------------------------------------------------------------
// K8: out = relu(GN2(out_raw)) + x   (in-place on d_out, float4)
// ---------------------------------------------------------------------------
__global__ __launch_bounds__(256) void k_final(const float* __restrict__ x,
        const float* __restrict__ sc2, const float* __restrict__ sh2,
        float* __restrict__ out) {
    int tid = blockIdx.x * blockDim.x + threadIdx.x;
    const int total4 = (BB * CHW) / 4;
    int stride = gridDim.x * blockDim.x;
    for (int i = tid; i < total4; i += stride) {
        int e = i * 4;
        int b = e >> 22;
        int o = (e >> 14) & 255;
        float s = sc2[b * 256 + o], h = sh2[b * 256 + o];
        float4 v = ((const float4*)out)[i];
        float4 xv = ((const float4*)x)[i];
        float4 r;
        r.x = fmaxf(fmaf(v.x, s, h), 0.f) + xv.x;
        r.y = fmaxf(fmaf(v.y, s, h), 0.f) + xv.y;
        r.z = fmaxf(fmaf(v.z, s, h), 0.f) + xv.z;
        r.w = fmaxf(fmaf(v.w, s, h), 0.f) + xv.w;
        ((float4*)out)[i] = r;
    }
}

// ---------------------------------------------------------------------------
extern "C" void kernel_launch(void* const* d_in, const int* in_sizes, int n_in,
                              void* d_out, int out_size, void* d_ws, size_t ws_size,
                              hipStream_t stream) {
    (void)in_sizes; (void)n_in; (void)out_size; (void)ws_size;
    const float* x   = (const float*)d_in[0];
    const float* W1  = (const float*)d_in[1];
    const float* W2  = (const float*)d_in[2];
    const float* c1w = (const float*)d_in[3];
    const float* c1b = (const float*)d_in[4];
    const float* c2w = (const float*)d_in[5];
    const float* c2b = (const float*)d_in[6];
    const float* g1w = (const float*)d_in[7];
    const float* g1b = (const float*)d_in[8];
    const float* gsw = (const float*)d_in[9];
    const float* gsb = (const float*)d_in[10];
    const float* g2w = (const float*)d_in[11];
    const float* g2b = (const float*)d_in[12];
    float* out = (float*)d_out;
    float* ws  = (float*)d_ws;

    float* t    = ws + WS_T;
    float* w2e  = ws + WS_W2E;
    float* k1e  = ws + WS_K1E;
    float* gn1a = ws + WS_GN1A;
    float* gnsa = ws + WS_GNSA;
    float* gn2a = ws + WS_GN2A;
    float* sc1  = ws + WS_SC1;
    float* sh1  = ws + WS_SH1;
    float* scs  = ws + WS_SCS;
    float* shs  = ws + WS_SHS;
    float* sc2  = ws + WS_SC2;
    float* sh2  = ws + WS_SH2;
    unsigned short* w1p = (unsigned short*)(ws + WS_W1P);
    unsigned short* w2p = (unsigned short*)(ws + WS_W2P);

    float* h1 = out;   // stash h1_raw (64 MB) in d_out; dead before conv2 overwrites

    k_setup<<<1, 128, 0, stream>>>(W1, W2, c1w, c2w, k1e, w2e, gn1a, w1p, w2p);
    k_conv1<<<1024, 256, 0, stream>>>(x, w1p, c1b, h1, gn1a);
    k_gnfin<<<4, 256, 0, stream>>>(gn1a, g1w, g1b, sc1, sh1, 1024, 6, 2, 1.f / 65536.f);
    k_x3<<<1024, 256, 0, stream>>>(h1, sc1, sh1, k1e, t);
    k_xsa<<<8192, 256, 0, stream>>>(h1, sc1, sh1, w2e, t, gnsa);
    k_gnfin<<<4, 256, 0, stream>>>(gnsa, gsw, gsb, scs, shs, 1024, 6, 2, 1.f / 65536.f);
    k_conv2<<<4096, 256, 0, stream>>>(t, scs, shs, w2p, c2b, out, gn2a);
    k_gnfin<<<16, 256, 0, stream>>>(gn2a, g2w, g2b, sc2, sh2, 4096, 8, 4, 1.f / 262144.f);
    k_final<<<2048, 256, 0, stream>>>(x, sc2, sh2, out);
}

// Round 4
// 422.215 us; speedup vs baseline: 2.6381x; 1.2206x over previous
//
#include <hip/hip_runtime.h>
#include <math.h>

// Problem constants
#define HW   16384        // 128*128
#define CC   256
#define cC   64
#define BB   16
#define CHW  (CC*HW)      // 4194304
#define cHW  (cC*HW)      // 1048576

// ws float offsets (ws_size = 1 GiB, verified via poison fill)
#define WS_TB    0                      // t bf16: 16*cHW ushorts = 8388608 floats
#define WS_H1B   8388608                // h1 bf16: same size
#define WS_RAWB  16777216               // conv2 raw bf16: 16*CHW ushorts = 33554432 floats
#define WS_W2E   50331648
#define WS_K1E   (WS_W2E + 5184)
#define WS_GN1A  (WS_K1E + 16)          // 512 floats
#define WS_GNSA  (WS_GN1A + 512)
#define WS_GN2A  (WS_GNSA + 512)
#define WS_SC1   (WS_GN2A + 512)        // 1024
#define WS_SH1   (WS_SC1 + 1024)
#define WS_SCS   (WS_SH1 + 1024)
#define WS_SHS   (WS_SCS + 1024)
#define WS_SC2   (WS_SHS + 1024)        // 4096
#define WS_SH2   (WS_SC2 + 4096)
#define WS_W1P   (WS_SH2 + 4096)        // 16384 ushort = 8192 floats
#define WS_W2P   (WS_W1P + 8192)        // 16384 ushort = 8192 floats

typedef __attribute__((ext_vector_type(8))) short bf16x8;
typedef __attribute__((ext_vector_type(4))) float f32x4;
typedef __attribute__((ext_vector_type(8))) unsigned short u16x8;

__device__ inline unsigned short f2bf(float f) {
    union { float f; unsigned u; } c; c.f = f;
    unsigned r = c.u + 0x7FFFu + ((c.u >> 16) & 1u);
    return (unsigned short)(r >> 16);
}
__device__ inline float bf2f(unsigned short h) {
    union { unsigned u; float f; } c; c.u = ((unsigned)h) << 16; return c.f;
}

// ---------------------------------------------------------------------------
// K0: effective kernels; zero GN accum; pack conv weights into MFMA frag order
// ---------------------------------------------------------------------------
__global__ void k_setup(const float* __restrict__ W1, const float* __restrict__ W2,
                        const float* __restrict__ c1w, const float* __restrict__ c2w,
                        float* __restrict__ k1e, float* __restrict__ w2e,
                        float* __restrict__ accz, unsigned short* __restrict__ w1p,
                        unsigned short* __restrict__ w2p) {
    __shared__ float tapsum[81];
    __shared__ float a2s[4];
    int tdx = threadIdx.x;
    for (int i = tdx; i < 1536; i += 128) accz[i] = 0.f;
    for (int e = tdx; e < 16384; e += 128) {
        int fi = e >> 9, rem = e & 511;
        int l = rem >> 3, j = rem & 7;
        int ks = fi >> 2, nf = fi & 3;
        int c = ks * 32 + (l >> 4) * 8 + j;
        int oc = nf * 16 + (l & 15);
        w1p[e] = f2bf(c1w[oc * 256 + c]);
    }
    for (int e = tdx; e < 16384; e += 128) {
        int fi = e >> 9, rem = e & 511;
        int l = rem >> 3, j = rem & 7;
        int ks = fi >> 4, nfg = fi & 15;
        int c = ks * 32 + (l >> 4) * 8 + j;
        int oc = nfg * 16 + (l & 15);
        w2p[e] = f2bf(c2w[oc * 64 + c]);
    }
    if (tdx < 81) {
        float s = 0.f;
        for (int ch = 0; ch < 64; ++ch) s += W2[ch * 81 + tdx];
        tapsum[tdx] = s;
    }
    __syncthreads();
    if (tdx == 0) {
        float ring[4] = {0.f, 0.f, 0.f, 0.f};
        for (int i = 0; i < 9; ++i)
            for (int j = 0; j < 9; ++j) {
                int d = max(abs(i - 4), abs(j - 4));
                int r = (d <= 1) ? 0 : (d - 1);
                ring[r] += tapsum[i * 9 + j];
            }
        float den2[4] = {576.f, 1024.f, 1536.f, 2048.f};
        float v[4], mx = -1e30f;
        for (int p = 0; p < 4; ++p) { v[p] = ring[p] / den2[p]; mx = fmaxf(mx, v[p]); }
        float se = 0.f;
        for (int p = 0; p < 4; ++p) { v[p] = expf(v[p] - mx); se += v[p]; }
        for (int p = 0; p < 4; ++p) a2s[p] = v[p] / se;
        float k1[9];
        for (int k = 0; k < 9; ++k) k1[k] = W1[k];
        float num[4];
        num[0] = k1[3] + k1[4] + k1[5];
        num[1] = k1[2] + k1[6];
        num[2] = k1[1] + k1[7];
        num[3] = k1[0] + k1[8];
        float den1[4] = {3.f, 2.f, 2.f, 2.f};
        mx = -1e30f;
        for (int p = 0; p < 4; ++p) { v[p] = num[p] / den1[p]; mx = fmaxf(mx, v[p]); }
        se = 0.f;
        for (int p = 0; p < 4; ++p) { v[p] = expf(v[p] - mx); se += v[p]; }
        float a1[4];
        for (int p = 0; p < 4; ++p) a1[p] = v[p] / se;
        float s1arr[5];
        s1arr[0] = 1.f; s1arr[1] = 1.f;
        s1arr[4] = a1[3]; s1arr[3] = a1[2] + a1[3]; s1arr[2] = a1[1] + s1arr[3];
        for (int k = 0; k < 9; ++k) { int d = abs(k - 4); k1e[k] = k1[k] * s1arr[d]; }
    }
    __syncthreads();
    float s2arr[5];
    s2arr[0] = 1.f; s2arr[1] = 1.f;
    s2arr[4] = a2s[3]; s2arr[3] = a2s[2] + a2s[3]; s2arr[2] = a2s[1] + s2arr[3];
    for (int idx = tdx; idx < 64 * 81; idx += 128) {
        int tap = idx % 81;
        int i = tap / 9, j = tap - i * 9;
        int d = max(abs(i - 4), abs(j - 4));
        w2e[idx] = W2[idx] * s2arr[d];
    }
}

// ---------------------------------------------------------------------------
// K1: conv1 (1x1, 256->64) via bf16 MFMA -> h1 bf16 [ch][p] ; GN1 sums
// ---------------------------------------------------------------------------
__global__ __launch_bounds__(256) void k_conv1(const float* __restrict__ x,
        const unsigned short* __restrict__ w1p, const float* __restrict__ b1,
        unsigned short* __restrict__ h1, float* __restrict__ gn1a) {
    int bid = blockIdx.x;
    int b = bid >> 6, pt = bid & 63;
    int tid = threadIdx.x;
    int w = tid >> 6, lane = tid & 63;
    int l15 = lane & 15, lg = lane >> 4;
    int p_wave = pt * 256 + w * 64;
    const bf16x8* w1v = (const bf16x8*)w1p;
    f32x4 acc[4][4];
#pragma unroll
    for (int mf = 0; mf < 4; ++mf)
#pragma unroll
        for (int nf = 0; nf < 4; ++nf) acc[mf][nf] = (f32x4){0.f, 0.f, 0.f, 0.f};
    const float* xb = x + b * CHW;
#pragma unroll 1
    for (int ks = 0; ks < 8; ++ks) {
        int c0 = ks * 32 + lg * 8;
        bf16x8 afr[4];
#pragma unroll
        for (int mf = 0; mf < 4; ++mf) {
            const float* xp = xb + c0 * HW + p_wave + mf * 16 + l15;
            bf16x8 a;
#pragma unroll
            for (int j = 0; j < 8; ++j) a[j] = (short)f2bf(xp[j * HW]);
            afr[mf] = a;
        }
#pragma unroll
        for (int nf = 0; nf < 4; ++nf) {
            bf16x8 bfr = w1v[(ks * 4 + nf) * 64 + lane];
#pragma unroll
            for (int mf = 0; mf < 4; ++mf)
                acc[mf][nf] = __builtin_amdgcn_mfma_f32_16x16x32_bf16(afr[mf], bfr, acc[mf][nf], 0, 0, 0);
        }
    }
    __shared__ float red[4][16][2];
    unsigned short* hb = h1 + b * cHW;
#pragma unroll
    for (int nf = 0; nf < 4; ++nf) {
        int oc = nf * 16 + l15;
        float bias = b1[oc];
        float s = 0.f, ss = 0.f;
#pragma unroll
        for (int mf = 0; mf < 4; ++mf) {
            f32x4 v = acc[mf][nf];
            v[0] += bias; v[1] += bias; v[2] += bias; v[3] += bias;
            ushort4 hv = make_ushort4(f2bf(v[0]), f2bf(v[1]), f2bf(v[2]), f2bf(v[3]));
            *(ushort4*)(hb + oc * HW + p_wave + mf * 16 + lg * 4) = hv;
            s += v[0] + v[1] + v[2] + v[3];
            ss += v[0] * v[0] + v[1] * v[1] + v[2] * v[2] + v[3] * v[3];
        }
        s += __shfl_xor(s, 16, 64); ss += __shfl_xor(ss, 16, 64);
        s += __shfl_xor(s, 32, 64); ss += __shfl_xor(ss, 32, 64);
        s += __shfl_xor(s, 1, 64);  ss += __shfl_xor(ss, 1, 64);
        s += __shfl_xor(s, 2, 64);  ss += __shfl_xor(ss, 2, 64);
        if (lg == 0 && (l15 & 3) == 0) {
            int g = nf * 4 + (l15 >> 2);
            red[w][g][0] = s; red[w][g][1] = ss;
        }
    }
    __syncthreads();
    if (tid < 32) {
        int g = tid >> 1, c = tid & 1;
        float v = red[0][g][c] + red[1][g][c] + red[2][g][c] + red[3][g][c];
        atomicAdd(&gn1a[(b * 16 + g) * 2 + c], v);
    }
}

// ---------------------------------------------------------------------------
// GN finalize
// ---------------------------------------------------------------------------
__global__ void k_gnfin(const float* __restrict__ accum, const float* __restrict__ gw,
                        const float* __restrict__ gb, float* __restrict__ scale,
                        float* __restrict__ shift, int nent, int chbits, int gshift,
                        float inv_n) {
    int idx = blockIdx.x * blockDim.x + threadIdx.x;
    if (idx >= nent) return;
    int chm = (1 << chbits) - 1;
    int ch = idx & chm, b = idx >> chbits, g = ch >> gshift;
    float s = accum[(b * 16 + g) * 2], ss = accum[(b * 16 + g) * 2 + 1];
    float mu = s * inv_n;
    float var = ss * inv_n - mu * mu;
    float rstd = rsqrtf(var + 1e-5f);
    float sc = gw[ch] * rstd;
    scale[idx] = sc;
    shift[idx] = gb[ch] - mu * sc;
}

// ---------------------------------------------------------------------------
// K3: channel-dim 9-tap conv (pad 4) of normalized h1 -> t (bf16)
// ---------------------------------------------------------------------------
__global__ __launch_bounds__(256) void k_x3(const unsigned short* __restrict__ h1,
        const float* __restrict__ scale1, const float* __restrict__ shift1,
        const float* __restrict__ k1e, unsigned short* __restrict__ t) {
    int idx = blockIdx.x * 256 + threadIdx.x;
    int b = idx >> 14, p = idx & 16383;
    const unsigned short* hb = h1 + b * cHW + p;
    const float* sc = scale1 + b * 64;
    const float* sh = shift1 + b * 64;
    float ke[9];
#pragma unroll
    for (int k = 0; k < 9; ++k) ke[k] = k1e[k];
    float win[9];
#pragma unroll
    for (int k = 0; k < 9; ++k) {
        int ch = k - 4;
        win[k] = (ch >= 0) ? fmaf(bf2f(hb[ch * HW]), sc[ch], sh[ch]) : 0.f;
    }
    unsigned short* tb = t + b * cHW + p;
#pragma unroll
    for (int ch = 0; ch < 64; ++ch) {
        float s = 0.f;
#pragma unroll
        for (int k = 0; k < 9; ++k) s = fmaf(win[k], ke[k], s);
        tb[ch * HW] = f2bf(s);
#pragma unroll
        for (int k = 0; k < 8; ++k) win[k] = win[k + 1];
        int nc = ch + 5;
        win[8] = (nc < 64) ? fmaf(bf2f(hb[nc * HW]), sc[nc], sh[nc]) : 0.f;
    }
}

// ---------------------------------------------------------------------------
// K4: depthwise 9x9 spatial conv ; t += x_sa (bf16 RMW) ; GN_s sums
// ---------------------------------------------------------------------------
__global__ __launch_bounds__(256) void k_xsa(const unsigned short* __restrict__ h1,
        const float* __restrict__ scale1, const float* __restrict__ shift1,
        const float* __restrict__ w2e, unsigned short* __restrict__ t,
        float* __restrict__ gnsa) {
    int bid = blockIdx.x;
    int b = bid >> 9, ch = (bid >> 3) & 63, rt = bid & 7;
    int r0 = rt * 16;
    const float sc = scale1[b * 64 + ch];
    const float sh = shift1[b * 64 + ch];
    const unsigned short* hp = h1 + b * cHW + ch * HW;
    __shared__ float tile[24 * 136];
    for (int li = threadIdx.x; li < 24 * 136; li += 256) {
        int row = li / 136, col = li - row * 136;
        int gr = r0 - 4 + row, gc = col - 4;
        float v = 0.f;
        if (gr >= 0 && gr < 128 && gc >= 0 && gc < 128)
            v = fmaf(bf2f(hp[gr * 128 + gc]), sc, sh);
        tile[li] = v;
    }
    __syncthreads();
    int q = threadIdx.x & 15, orow = threadIdx.x >> 4;
    const float* wch = w2e + ch * 81;
    float acc[2][4] = {{0.f, 0.f, 0.f, 0.f}, {0.f, 0.f, 0.f, 0.f}};
#pragma unroll
    for (int i = 0; i < 9; ++i) {
#pragma unroll
        for (int m = 0; m < 2; ++m) {
            int c0 = q * 4 + m * 64;
            const float* lr = &tile[(orow + i) * 136 + c0];
            float v[12];
            *(float4*)&v[0] = *(const float4*)lr;
            *(float4*)&v[4] = *(const float4*)(lr + 4);
            *(float4*)&v[8] = *(const float4*)(lr + 8);
#pragma unroll
            for (int j = 0; j < 9; ++j) {
                float wv = wch[i * 9 + j];
                acc[m][0] = fmaf(v[j], wv, acc[m][0]);
                acc[m][1] = fmaf(v[j + 1], wv, acc[m][1]);
                acc[m][2] = fmaf(v[j + 2], wv, acc[m][2]);
                acc[m][3] = fmaf(v[j + 3], wv, acc[m][3]);
            }
        }
    }
    float s = 0.f, ss = 0.f;
    unsigned short* tp = t + b * cHW + ch * HW + (r0 + orow) * 128;
#pragma unroll
    for (int m = 0; m < 2; ++m) {
        int c0 = q * 4 + m * 64;
        ushort4 tv = *(const ushort4*)(tp + c0);
        float r0v = bf2f(tv.x) + acc[m][0];
        float r1v = bf2f(tv.y) + acc[m][1];
        float r2v = bf2f(tv.z) + acc[m][2];
        float r3v = bf2f(tv.w) + acc[m][3];
        *(ushort4*)(tp + c0) = make_ushort4(f2bf(r0v), f2bf(r1v), f2bf(r2v), f2bf(r3v));
        s += r0v + r1v + r2v + r3v;
        ss += r0v * r0v + r1v * r1v + r2v * r2v + r3v * r3v;
    }
#pragma unroll
    for (int off = 32; off; off >>= 1) { s += __shfl_xor(s, off, 64); ss += __shfl_xor(ss, off, 64); }
    __shared__ float rs[4], rss[4];
    int lane = threadIdx.x & 63, wv2 = threadIdx.x >> 6;
    if (lane == 0) { rs[wv2] = s; rss[wv2] = ss; }
    __syncthreads();
    if (threadIdx.x == 0) {
        int gi = (b * 16 + (ch >> 2)) * 2;
        atomicAdd(&gnsa[gi], rs[0] + rs[1] + rs[2] + rs[3]);
        atomicAdd(&gnsa[gi + 1], rss[0] + rss[1] + rss[2] + rss[3]);
    }
}

// ---------------------------------------------------------------------------
// K6: conv2 (1x1, 64->256) via bf16 MFMA ; relu(GN_s) fused ; raw out bf16 ;
//     GN2 sums
// ---------------------------------------------------------------------------
__global__ __launch_bounds__(256) void k_conv2(const unsigned short* __restrict__ t,
        const float* __restrict__ scs, const float* __restrict__ shs,
        const unsigned short* __restrict__ w2p, const float* __restrict__ b2,
        unsigned short* __restrict__ raw, float* __restrict__ gn2a) {
    int bid = blockIdx.x;
    int obk = bid & 1, pt = (bid >> 1) & 127, b = bid >> 8;
    int tid = threadIdx.x;
    int w = tid >> 6, lane = tid & 63;
    int l15 = lane & 15, lg = lane >> 4;
    int pw = w >> 1, ow = w & 1;
    int p_wave = pt * 128 + pw * 64;
    __shared__ float lsc[64], lsh[64];
    __shared__ float red[4][4][2];
    if (tid < 64) { lsc[tid] = scs[b * 64 + tid]; lsh[tid] = shs[b * 64 + tid]; }
    __syncthreads();
    const bf16x8* w2v = (const bf16x8*)w2p;
    f32x4 acc[4][4];
#pragma unroll
    for (int mf = 0; mf < 4; ++mf)
#pragma unroll
        for (int nf = 0; nf < 4; ++nf) acc[mf][nf] = (f32x4){0.f, 0.f, 0.f, 0.f};
    const unsigned short* tb = t + b * cHW;
#pragma unroll
    for (int ks = 0; ks < 2; ++ks) {
        int kb = ks * 32 + lg * 8;
        float kc[8], kh[8];
#pragma unroll
        for (int j = 0; j < 8; ++j) { kc[j] = lsc[kb + j]; kh[j] = lsh[kb + j]; }
        bf16x8 afr[4];
#pragma unroll
        for (int mf = 0; mf < 4; ++mf) {
            const unsigned short* tp = tb + kb * HW + p_wave + mf * 16 + l15;
            bf16x8 a;
#pragma unroll
            for (int j = 0; j < 8; ++j) {
                float v = fmaxf(fmaf(bf2f(tp[j * HW]), kc[j], kh[j]), 0.f);
                a[j] = (short)f2bf(v);
            }
            afr[mf] = a;
        }
#pragma unroll
        for (int nf = 0; nf < 4; ++nf) {
            int fi = ks * 16 + (obk * 8 + ow * 4 + nf);
            bf16x8 bfr = w2v[fi * 64 + lane];
#pragma unroll
            for (int mf = 0; mf < 4; ++mf)
                acc[mf][nf] = __builtin_amdgcn_mfma_f32_16x16x32_bf16(afr[mf], bfr, acc[mf][nf], 0, 0, 0);
        }
    }
    int oc0 = obk * 128 + ow * 64;
    unsigned short* ob = raw + b * CHW;
    float sred[4], ssred[4];
#pragma unroll
    for (int nf = 0; nf < 4; ++nf) {
        int oc = oc0 + nf * 16 + l15;
        float bias = b2[oc];
        float s = 0.f, ss = 0.f;
#pragma unroll
        for (int mf = 0; mf < 4; ++mf) {
            f32x4 v = acc[mf][nf];
            v[0] += bias; v[1] += bias; v[2] += bias; v[3] += bias;
            ushort4 hv = make_ushort4(f2bf(v[0]), f2bf(v[1]), f2bf(v[2]), f2bf(v[3]));
            *(ushort4*)(ob + oc * HW + p_wave + mf * 16 + lg * 4) = hv;
            s += v[0] + v[1] + v[2] + v[3];
            ss += v[0] * v[0] + v[1] * v[1] + v[2] * v[2] + v[3] * v[3];
        }
#pragma unroll
        for (int off = 32; off; off >>= 1) { s += __shfl_xor(s, off, 64); ss += __shfl_xor(ss, off, 64); }
        sred[nf] = s; ssred[nf] = ss;
    }
    if (lane == 0) {
#pragma unroll
        for (int nf = 0; nf < 4; ++nf) { red[w][nf][0] = sred[nf]; red[w][nf][1] = ssred[nf]; }
    }
    __syncthreads();
    if (tid < 16) {
        int ow2 = tid >> 3, nf = (tid >> 1) & 3, c = tid & 1;
        float v = red[ow2][nf][c] + red[ow2 + 2][nf][c];
        int g = obk * 8 + ow2 * 4 + nf;
        atomicAdd(&gn2a[(b * 16 + g) * 2 + c], v);
    }
}

// ---------------------------------------------------------------------------
// K8: out = relu(GN2(raw)) + x   (raw bf16, 8 elems/iter)
// ---------------------------------------------------------------------------
__global__ __launch_bounds__(256) void k_final(const float* __restrict__ x,
        const unsigned short* __restrict__ raw,
        const float* __restrict__ sc2, const float* __restrict__ sh2,
        float* __restrict__ out) {
    int tid = blockIdx.x * blockDim.x + threadIdx.x;
    const int total8 = (BB * CHW) / 8;
    int stride = gridDim.x * blockDim.x;
    for (int i = tid; i < total8; i += stride) {
        int e = i * 8;
        int b = e >> 22;
        int o = (e >> 14) & 255;
        float s = sc2[b * 256 + o], h = sh2[b * 256 + o];
        u16x8 rv = ((const u16x8*)raw)[i];
        float4 xa = ((const float4*)x)[2 * i];
        float4 xb = ((const float4*)x)[2 * i + 1];
        float4 r0, r1;
        r0.x = fmaxf(fmaf(bf2f(rv[0]), s, h), 0.f) + xa.x;
        r0.y = fmaxf(fmaf(bf2f(rv[1]), s, h), 0.f) + xa.y;
        r0.z = fmaxf(fmaf(bf2f(rv[2]), s, h), 0.f) + xa.z;
        r0.w = fmaxf(fmaf(bf2f(rv[3]), s, h), 0.f) + xa.w;
        r1.x = fmaxf(fmaf(bf2f(rv[4]), s, h), 0.f) + xb.x;
        r1.y = fmaxf(fmaf(bf2f(rv[5]), s, h), 0.f) + xb.y;
        r1.z = fmaxf(fmaf(bf2f(rv[6]), s, h), 0.f) + xb.z;
        r1.w = fmaxf(fmaf(bf2f(rv[7]), s, h), 0.f) + xb.w;
        ((float4*)out)[2 * i] = r0;
        ((float4*)out)[2 * i + 1] = r1;
    }
}

// ---------------------------------------------------------------------------
extern "C" void kernel_launch(void* const* d_in, const int* in_sizes, int n_in,
                              void* d_out, int out_size, void* d_ws, size_t ws_size,
                              hipStream_t stream) {
    (void)in_sizes; (void)n_in; (void)out_size; (void)ws_size;
    const float* x   = (const float*)d_in[0];
    const float* W1  = (const float*)d_in[1];
    const float* W2  = (const float*)d_in[2];
    const float* c1w = (const float*)d_in[3];
    const float* c1b = (const float*)d_in[4];
    const float* c2w = (const float*)d_in[5];
    const float* c2b = (const float*)d_in[6];
    const float* g1w = (const float*)d_in[7];
    const float* g1b = (const float*)d_in[8];
    const float* gsw = (const float*)d_in[9];
    const float* gsb = (const float*)d_in[10];
    const float* g2w = (const float*)d_in[11];
    const float* g2b = (const float*)d_in[12];
    float* out = (float*)d_out;
    float* ws  = (float*)d_ws;

    unsigned short* tb   = (unsigned short*)(ws + WS_TB);
    unsigned short* h1b  = (unsigned short*)(ws + WS_H1B);
    unsigned short* rawb = (unsigned short*)(ws + WS_RAWB);
    float* w2e  = ws + WS_W2E;
    float* k1e  = ws + WS_K1E;
    float* gn1a = ws + WS_GN1A;
    float* gnsa = ws + WS_GNSA;
    float* gn2a = ws + WS_GN2A;
    float* sc1  = ws + WS_SC1;
    float* sh1  = ws + WS_SH1;
    float* scs  = ws + WS_SCS;
    float* shs  = ws + WS_SHS;
    float* sc2  = ws + WS_SC2;
    float* sh2  = ws + WS_SH2;
    unsigned short* w1p = (unsigned short*)(ws + WS_W1P);
    unsigned short* w2p = (unsigned short*)(ws + WS_W2P);

    k_setup<<<1, 128, 0, stream>>>(W1, W2, c1w, c2w, k1e, w2e, gn1a, w1p, w2p);
    k_conv1<<<1024, 256, 0, stream>>>(x, w1p, c1b, h1b, gn1a);
    k_gnfin<<<4, 256, 0, stream>>>(gn1a, g1w, g1b, sc1, sh1, 1024, 6, 2, 1.f / 65536.f);
    k_x3<<<1024, 256, 0, stream>>>(h1b, sc1, sh1, k1e, tb);
    k_xsa<<<8192, 256, 0, stream>>>(h1b, sc1, sh1, w2e, tb, gnsa);
    k_gnfin<<<4, 256, 0, stream>>>(gnsa, gsw, gsb, scs, shs, 1024, 6, 2, 1.f / 65536.f);
    k_conv2<<<4096, 256, 0, stream>>>(tb, scs, shs, w2p, c2b, rawb, gn2a);
    k_gnfin<<<16, 256, 0, stream>>>(gn2a, g2w, g2b, sc2, sh2, 4096, 8, 4, 1.f / 262144.f);
    k_final<<<2048, 256, 0, stream>>>(x, rawb, sc2, sh2, out);
}